// Round 9
// baseline (343.305 us; speedup 1.0000x reference)
//
#include <hip/hip_runtime.h>
#include <stdint.h>

#define TS 2048
#define DM 2048
#define NH 16
#define DH 128

typedef unsigned short u16t;
typedef __attribute__((ext_vector_type(8))) short short8;
typedef __attribute__((ext_vector_type(4))) float f32x4;
typedef __attribute__((ext_vector_type(4))) unsigned int u32x4;

__device__ __forceinline__ float bf2f(u16t b) {
  return __uint_as_float(((unsigned int)b) << 16);
}
__device__ __forceinline__ u16t f2bf(float f) {
  unsigned int u = __float_as_uint(f);
  u += 0x7FFFu + ((u >> 16) & 1u);   // round-to-nearest-even
  return (u16t)(u >> 16);
}

// async global->LDS, 16B per lane. LDS dest = wave-uniform base + lane*16.
__device__ __forceinline__ void async_copy16(const u16t* g, u16t* l) {
  __builtin_amdgcn_global_load_lds((const __attribute__((address_space(1))) void*)g,
                                   (__attribute__((address_space(3))) void*)l, 16, 0, 0);
}

// DPP row_ror within 16-lane rows: pure-VALU cross-lane (vs ds_bpermute for __shfl).
#define DPP_ROR_F(x, n) __uint_as_float(__builtin_amdgcn_update_dpp( \
    0, (int)__float_as_uint(x), 0x120 | (n), 0xF, 0xF, true))

__device__ __forceinline__ float row16_max(float x) {
  x = fmaxf(x, DPP_ROR_F(x, 8));
  x = fmaxf(x, DPP_ROR_F(x, 4));
  x = fmaxf(x, DPP_ROR_F(x, 2));
  x = fmaxf(x, DPP_ROR_F(x, 1));
  return x;
}
__device__ __forceinline__ float row16_sum(float x) {
  x += DPP_ROR_F(x, 8);
  x += DPP_ROR_F(x, 4);
  x += DPP_ROR_F(x, 2);
  x += DPP_ROR_F(x, 1);
  return x;
}

// ---------------- fp32 weights -> bf16 (4 matrices, ws) ----------------
__global__ __launch_bounds__(256) void cast_weights(const float* __restrict__ W0,
                                                    const float* __restrict__ W1,
                                                    const float* __restrict__ W2,
                                                    const float* __restrict__ W3,
                                                    u16t* __restrict__ out) {
  const int idx = blockIdx.x * 256 + threadIdx.x;   // 4M threads, 4 elems each
  const int mat = idx >> 20;
  const size_t off = (size_t)(idx & 0xFFFFF) * 4;
  const float* W = (mat == 0) ? W0 : (mat == 1) ? W1 : (mat == 2) ? W2 : W3;
  const f32x4 v = *(const f32x4*)(W + off);
  union { u16t s[4]; uint64_t u; } o;
#pragma unroll
  for (int i = 0; i < 4; ++i) o.s[i] = f2bf(v[i]);
  *(uint64_t*)(out + (size_t)mat * (DM * DM) + off) = o.u;
}

// ---------------- RMSNorm: h = bf16( ln_w * x * rsqrt(mean(x^2)+eps) ) ----------------
__global__ __launch_bounds__(256) void rmsnorm_kernel(const float* __restrict__ x,
                                                      const float* __restrict__ w,
                                                      u16t* __restrict__ h) {
  const int row = blockIdx.x;
  const int tid = threadIdx.x;
  const float* xr = x + (size_t)row * DM + tid * 8;
  f32x4 v0 = *(const f32x4*)(xr);
  f32x4 v1 = *(const f32x4*)(xr + 4);
  float f[8];
#pragma unroll
  for (int i = 0; i < 4; ++i) { f[i] = v0[i]; f[i + 4] = v1[i]; }
  float ss = 0.f;
#pragma unroll
  for (int i = 0; i < 8; ++i) ss += f[i] * f[i];
#pragma unroll
  for (int off = 1; off < 64; off <<= 1) ss += __shfl_xor(ss, off, 64);
  __shared__ float wsum[4];
  if ((tid & 63) == 0) wsum[tid >> 6] = ss;
  __syncthreads();
  float tot = wsum[0] + wsum[1] + wsum[2] + wsum[3];
  float rs = rsqrtf(tot * (1.0f / DM) + 1e-5f);
  f32x4 w0 = *(const f32x4*)(w + tid * 8);
  f32x4 w1 = *(const f32x4*)(w + tid * 8 + 4);
  u32x4 o;
#pragma unroll
  for (int i = 0; i < 4; ++i) {
    unsigned int lo = f2bf(f[2 * i]     * ((2 * i     < 4) ? w0[2 * i]     : w1[2 * i - 4]) * rs);
    unsigned int hi = f2bf(f[2 * i + 1] * ((2 * i + 1 < 4) ? w0[2 * i + 1] : w1[2 * i - 3]) * rs);
    o[i] = lo | (hi << 16);
  }
  *(u32x4*)(h + (size_t)row * DM + tid * 8) = o;
}

// ---------------- GEMM C = A * B^T (bf16 A,B row-major, K contiguous) ----------------
// Round-3 structure: 128x128 tile, BK=32, 4 waves each 64x64 (4x4 of 16x16x32 MFMA).
// 6.3M LDS bank conflicts measured harmless (r4); epilogue fusions measured harmful (r5).
// MODE 0: QKV fused via blockIdx.z (z==2 stores transposed for Vt); bf16 C.
// MODE 1: out-proj split-K=2 via blockIdx.z: plain fp32 partial store to C0/C1.
template <int MODE>
__global__ __launch_bounds__(256) void gemm_bt(
    const u16t* __restrict__ A,
    const u16t* __restrict__ B0, const u16t* __restrict__ B1, const u16t* __restrict__ B2,
    void* __restrict__ C0, void* __restrict__ C1, void* __restrict__ C2) {
  __shared__ u16t Alds[128 * 32];
  __shared__ u16t Blds[128 * 32];
  const int tid  = threadIdx.x;
  const int wave = tid >> 6;
  const int lane = tid & 63;
  const int m0 = blockIdx.y * 128;
  const int n0 = blockIdx.x * 128;
  const int z  = blockIdx.z;
  const u16t* B = (MODE == 0) ? (z == 0 ? B0 : (z == 1 ? B1 : B2)) : B0;
  const int kbeg = (MODE == 1) ? z * (DM / 2) : 0;
  const int kend = (MODE == 1) ? kbeg + (DM / 2) : DM;

  const f32x4 fzero = {0.f, 0.f, 0.f, 0.f};
  f32x4 acc[4][4];
#pragma unroll
  for (int i = 0; i < 4; ++i)
#pragma unroll
    for (int j = 0; j < 4; ++j) acc[i][j] = fzero;

  const int lr = lane >> 2;   // 0..15 row within 16-row chunk
  const int lc = lane & 3;    // 0..3  8-elem column chunk
  const int mw = (wave >> 1) * 64;
  const int nw = (wave & 1) * 64;
  const int quad = lane >> 4;
  const int c16  = lane & 15;

  for (int k0 = kbeg; k0 < kend; k0 += 32) {
    __syncthreads();
#pragma unroll
    for (int c = 0; c < 2; ++c) {
      const int ch = wave * 2 + c;        // 8 chunks of 1KB each per tile
      const int r  = ch * 16 + lr;
      async_copy16(A + (size_t)(m0 + r) * DM + k0 + lc * 8, Alds + ch * 512);
      async_copy16(B + (size_t)(n0 + r) * DM + k0 + lc * 8, Blds + ch * 512);
    }
    __syncthreads();
    short8 af[4], bfr[4];
#pragma unroll
    for (int mt = 0; mt < 4; ++mt)
      af[mt] = *(const short8*)(Alds + (mw + mt * 16 + c16) * 32 + quad * 8);
#pragma unroll
    for (int nt = 0; nt < 4; ++nt)
      bfr[nt] = *(const short8*)(Blds + (nw + nt * 16 + c16) * 32 + quad * 8);
#pragma unroll
    for (int mt = 0; mt < 4; ++mt)
#pragma unroll
      for (int nt = 0; nt < 4; ++nt)
        acc[mt][nt] = __builtin_amdgcn_mfma_f32_16x16x32_bf16(af[mt], bfr[nt], acc[mt][nt], 0, 0, 0);
  }

#pragma unroll
  for (int mt = 0; mt < 4; ++mt) {
#pragma unroll
    for (int r = 0; r < 4; ++r) {
      const int row = m0 + mw + mt * 16 + quad * 4 + r;
#pragma unroll
      for (int nt = 0; nt < 4; ++nt) {
        const int col = n0 + nw + nt * 16 + c16;
        float vv = acc[mt][nt][r];
        if (MODE == 1) {
          float* C = (float*)(z == 0 ? C0 : C1);
          C[(size_t)row * DM + col] = vv;
        } else {
          u16t* C = (u16t*)(z == 0 ? C0 : (z == 1 ? C1 : C2));
          if (z == 2) C[(size_t)col * TS + row] = f2bf(vv);   // Vt[d_global][t]
          else        C[(size_t)row * DM + col] = f2bf(vv);
        }
      }
    }
  }
}

// ---------------- combine: out = x + mask_row * (P0 + P1) ----------------
__global__ __launch_bounds__(256) void combine_kernel(const float* __restrict__ P0,
                                                      const float* __restrict__ P1,
                                                      const float* __restrict__ x,
                                                      const int* __restrict__ am,
                                                      float* __restrict__ out) {
  const size_t idx = ((size_t)blockIdx.x * 256 + threadIdx.x) * 4;
  const int row = (int)(idx >> 11);           // idx / DM
  const float mk = (am[row] != 0) ? 1.f : 0.f;
  const f32x4 a = *(const f32x4*)(P0 + idx);
  const f32x4 b = *(const f32x4*)(P1 + idx);
  const f32x4 xr = *(const f32x4*)(x + idx);
  f32x4 o;
#pragma unroll
  for (int i = 0; i < 4; ++i) o[i] = xr[i] + mk * (a[i] + b[i]);
  *(f32x4*)(out + idx) = o;
}

// ---------------- RoPE in-place on Q and K (bf16), fp32 cos/sin ----------------
__global__ __launch_bounds__(256) void rope_kernel(u16t* __restrict__ Q, u16t* __restrict__ K,
                                                   const float* __restrict__ cosb,
                                                   const float* __restrict__ sinb) {
  int idx = blockIdx.x * 256 + threadIdx.x;   // 2 * 2048 * 1024 threads
  int mat = idx >> 21;
  int rem = idx & ((1 << 21) - 1);
  int t = rem >> 10;
  int p = rem & 1023;
  int head = p >> 6, d = p & 63;
  u16t* M = mat ? K : Q;
  size_t base = (size_t)t * DM + head * DH + d;
  float c = cosb[t * DH + d];
  float s = sinb[t * DH + d];
  float x1 = bf2f(M[base]);
  float x2 = bf2f(M[base + 64]);
  M[base]      = f2bf(x1 * c - x2 * s);
  M[base + 64] = f2bf(x2 * c + x1 * s);
}

// ---------------- Flash attention (causal), 128-q-row blocks x 8 waves ----------------
// Each staged 128-key K/V tile (64 KB) now feeds 128 q-rows (2x r7) -> total LDS-staging
// volume halves (~300 -> ~140 MB). Per-wave inner code identical to r7 (16 q-rows/wave,
// DPP softmax, P round-trip). 256 blocks x 512 threads, LDS 96 KB -> 1 block/CU,
// 2 waves/SIMD for MFMA/VALU overlap.
__global__ __launch_bounds__(512) void attn_kernel(const u16t* __restrict__ Q,
                                                   const u16t* __restrict__ K,
                                                   const u16t* __restrict__ Vt,
                                                   const int* __restrict__ am,
                                                   u16t* __restrict__ O) {
  __shared__ u16t Klds[128 * 128];   // [key][d], swizzled granules, 32 KB
  __shared__ u16t Vlds[128 * 128];   // [d][key], swizzled granules, 32 KB
  __shared__ u16t Plds[8][2048];     // per-wave P: 4 chunks of 16x32, 32 KB
  const int wave = threadIdx.x >> 6;             // 0..7
  const int lane = threadIdx.x & 63;
  const int head = blockIdx.x & (NH - 1);
  const int qt   = (TS / 128 - 1) - (blockIdx.x >> 4);   // largest q-tiles first
  const int q0   = qt * 128 + wave * 16;
  const int quad = lane >> 4;
  const int c16  = lane & 15;
  const u16t* Qh  = Q + head * DH;
  const u16t* Kh  = K + head * DH;
  const u16t* Vth = Vt + (size_t)head * DH * TS;
  u16t* Pw = Plds[wave];

  // staging lane constants: chunk = 4 rows x 16 granules (16B each)
  const int row_s = (lane >> 4);    // 0..3 row within chunk
  const int g_s   = (lane & 15);    // granule slot

  short8 qf[4];
#pragma unroll
  for (int dc = 0; dc < 4; ++dc)
    qf[dc] = *(const short8*)(Qh + (size_t)(q0 + c16) * DM + dc * 32 + quad * 8);

  const f32x4 fzero = {0.f, 0.f, 0.f, 0.f};
  float m_run[4], l_run[4];
  f32x4 o_acc[8];
#pragma unroll
  for (int r = 0; r < 4; ++r) { m_run[r] = -1e30f; l_run[r] = 0.f; }
#pragma unroll
  for (int nt = 0; nt < 8; ++nt) o_acc[nt] = fzero;

  const float scale = 0.08838834764831845f;  // 1/sqrt(128)
  const int ntiles = qt + 1;                 // 128-wide tiles cover keys 0..qt*128+127

  for (int kt = 0; kt < ntiles; ++kt) {
    const int k0 = kt * 128;
    __syncthreads();   // all waves done reading previous K/V tile
    // stage K (32 chunks of 1KB) + V (32 chunks): 4+4 per wave
#pragma unroll
    for (int c = 0; c < 4; ++c) {
      const int ch = wave * 4 + c;             // 0..31
      const int r  = 4 * ch + row_s;           // 0..127
      const int g  = g_s ^ (r & 15);
      async_copy16(Kh + (size_t)(k0 + r) * DM + g * 8, Klds + ch * 512);
      async_copy16(Vth + (size_t)r * TS + k0 + g * 8, Vlds + ch * 512);
    }
    __syncthreads();   // drains vmcnt -> LDS tiles ready

    // S = Q K^T over 128 keys (8 groups of 16)
    f32x4 s[8];
#pragma unroll
    for (int ns = 0; ns < 8; ++ns) {
      f32x4 sa = fzero;
      const int rr = ns * 16 + c16;
#pragma unroll
      for (int dc = 0; dc < 4; ++dc) {
        short8 kf = *(const short8*)(Klds + rr * 128 + (((dc * 4 + quad) ^ c16) * 8));
        sa = __builtin_amdgcn_mfma_f32_16x16x32_bf16(qf[dc], kf, sa, 0, 0, 0);
      }
      s[ns] = sa;
    }

    // mask + scale + online softmax (DPP rotate-reduce within each 16-lane row)
    float pv[8][4], tmax[4];
#pragma unroll
    for (int r = 0; r < 4; ++r) tmax[r] = -1e30f;
#pragma unroll
    for (int ns = 0; ns < 8; ++ns) {
      const int key = k0 + ns * 16 + c16;
      const bool kok = (am[key] != 0);
#pragma unroll
      for (int r = 0; r < 4; ++r) {
        const int qrow = q0 + quad * 4 + r;
        float v = s[ns][r] * scale;
        if (key > qrow || !kok) v = -1e30f;
        pv[ns][r] = v;
        tmax[r] = fmaxf(tmax[r], v);
      }
    }
    float alpha[4], rsum[4];
#pragma unroll
    for (int r = 0; r < 4; ++r) {
      const float mn = fmaxf(m_run[r], row16_max(tmax[r]));
      alpha[r] = __expf(m_run[r] - mn);
      m_run[r] = mn;
      float rs = 0.f;
#pragma unroll
      for (int ns = 0; ns < 8; ++ns) {
        const float e = __expf(pv[ns][r] - mn);
        pv[ns][r] = e;
        rs += e;
      }
      rsum[r] = row16_sum(rs);
      l_run[r] = l_run[r] * alpha[r] + rsum[r];
    }

    // P: C-layout -> LDS (four 16x32 chunks) -> A-layout
#pragma unroll
    for (int ns = 0; ns < 8; ++ns)
#pragma unroll
      for (int r = 0; r < 4; ++r)
        Pw[(ns >> 1) * 512 + (quad * 4 + r) * 32 + (ns & 1) * 16 + c16] = f2bf(pv[ns][r]);
    asm volatile("s_waitcnt lgkmcnt(0)" ::: "memory");
    short8 pf[4];
#pragma unroll
    for (int c = 0; c < 4; ++c)
      pf[c] = *(const short8*)(Pw + c * 512 + c16 * 32 + quad * 8);

    // rescale O then accumulate P*V over 128 keys
#pragma unroll
    for (int nt = 0; nt < 8; ++nt)
#pragma unroll
      for (int r = 0; r < 4; ++r) o_acc[nt][r] *= alpha[r];
#pragma unroll
    for (int nt = 0; nt < 8; ++nt) {
      const int rr = nt * 16 + c16;
#pragma unroll
      for (int c = 0; c < 4; ++c) {
        short8 vf = *(const short8*)(Vlds + rr * 128 + (((c * 4 + quad) ^ c16) * 8));
        o_acc[nt] = __builtin_amdgcn_mfma_f32_16x16x32_bf16(pf[c], vf, o_acc[nt], 0, 0, 0);
      }
    }
  }

  // epilogue: O / l
#pragma unroll
  for (int r = 0; r < 4; ++r) {
    const float inv = 1.0f / fmaxf(l_run[r], 1e-20f);
    const int qrow = q0 + quad * 4 + r;
#pragma unroll
    for (int nt = 0; nt < 8; ++nt)
      O[(size_t)qrow * DM + head * DH + nt * 16 + c16] = f2bf(o_acc[nt][r] * inv);
  }
}

extern "C" void kernel_launch(void* const* d_in, const int* in_sizes, int n_in,
                              void* d_out, int out_size, void* d_ws, size_t ws_size,
                              hipStream_t stream) {
  const float* x    = (const float*)d_in[0];
  const float* cosb = (const float*)d_in[1];
  const float* sinb = (const float*)d_in[2];
  const int*   am   = (const int*)d_in[3];
  const float* lnw  = (const float*)d_in[4];
  const float* Wq   = (const float*)d_in[5];
  const float* Wk   = (const float*)d_in[6];
  const float* Wv   = (const float*)d_in[7];
  const float* Wo   = (const float*)d_in[8];
  float* out = (float*)d_out;

  u16t* h    = (u16t*)d_ws;                 // (T, D) bf16   [0, 8 MB)
  u16t* Q    = h + (size_t)TS * DM;         // (T, D)        [8, 16)
  u16t* K    = Q + (size_t)TS * DM;         // (T, D)        [16, 24)
  u16t* Vt   = K + (size_t)TS * DM;         // (D, T)        [24, 32)
  u16t* attn = Vt + (size_t)TS * DM;        // (T, D)        [32, 40)
  u16t* Wb   = attn + (size_t)TS * DM;      // 4 x (D, D)    [40, 72)
  u16t* Wqb = Wb;
  u16t* Wkb = Wb + (size_t)DM * DM;
  u16t* Wvb = Wb + 2 * (size_t)DM * DM;
  u16t* Wob = Wb + 3 * (size_t)DM * DM;
  // split-K partials alias h/Q (P0) and K/Vt (P1) — dead by out-proj time
  float* P0 = (float*)d_ws;                          // 16 MB fp32
  float* P1 = (float*)(((u16t*)d_ws) + 2 * (size_t)TS * DM);

  cast_weights<<<(4 * DM * DM / 4) / 256, 256, 0, stream>>>(Wq, Wk, Wv, Wo, Wb);
  rmsnorm_kernel<<<TS, 256, 0, stream>>>(x, lnw, h);
  gemm_bt<0><<<dim3(16, 16, 3), 256, 0, stream>>>(h, Wqb, Wkb, Wvb, Q, K, Vt);
  rope_kernel<<<(2 * TS * 1024) / 256, 256, 0, stream>>>(Q, K, cosb, sinb);
  attn_kernel<<<NH * (TS / 128), 512, 0, stream>>>(Q, K, Vt, am, attn);
  gemm_bt<1><<<dim3(16, 16, 2), 256, 0, stream>>>(attn, Wob, nullptr, nullptr, P0, P1, nullptr);
  combine_kernel<<<(TS * DM / 4) / 256, 256, 0, stream>>>(P0, P1, x, am, out);
}

// Round 10
// 331.359 us; speedup vs baseline: 1.0360x; 1.0360x over previous
//
#include <hip/hip_runtime.h>
#include <stdint.h>

#define TS 2048
#define DM 2048
#define NH 16
#define DH 128

typedef unsigned short u16t;
typedef __attribute__((ext_vector_type(8))) short short8;
typedef __attribute__((ext_vector_type(4))) float f32x4;
typedef __attribute__((ext_vector_type(4))) unsigned int u32x4;

__device__ __forceinline__ float bf2f(u16t b) {
  return __uint_as_float(((unsigned int)b) << 16);
}
__device__ __forceinline__ u16t f2bf(float f) {
  unsigned int u = __float_as_uint(f);
  u += 0x7FFFu + ((u >> 16) & 1u);   // round-to-nearest-even
  return (u16t)(u >> 16);
}

// async global->LDS, 16B per lane. LDS dest = wave-uniform base + lane*16.
__device__ __forceinline__ void async_copy16(const u16t* g, u16t* l) {
  __builtin_amdgcn_global_load_lds((const __attribute__((address_space(1))) void*)g,
                                   (__attribute__((address_space(3))) void*)l, 16, 0, 0);
}

// DPP row_ror within 16-lane rows: pure-VALU cross-lane (vs ds_bpermute for __shfl).
#define DPP_ROR_F(x, n) __uint_as_float(__builtin_amdgcn_update_dpp( \
    0, (int)__float_as_uint(x), 0x120 | (n), 0xF, 0xF, true))

__device__ __forceinline__ float row16_max(float x) {
  x = fmaxf(x, DPP_ROR_F(x, 8));
  x = fmaxf(x, DPP_ROR_F(x, 4));
  x = fmaxf(x, DPP_ROR_F(x, 2));
  x = fmaxf(x, DPP_ROR_F(x, 1));
  return x;
}
__device__ __forceinline__ float row16_sum(float x) {
  x += DPP_ROR_F(x, 8);
  x += DPP_ROR_F(x, 4);
  x += DPP_ROR_F(x, 2);
  x += DPP_ROR_F(x, 1);
  return x;
}

// ---------------- fp32 weights -> bf16 (4 matrices, ws) ----------------
__global__ __launch_bounds__(256) void cast_weights(const float* __restrict__ W0,
                                                    const float* __restrict__ W1,
                                                    const float* __restrict__ W2,
                                                    const float* __restrict__ W3,
                                                    u16t* __restrict__ out) {
  const int idx = blockIdx.x * 256 + threadIdx.x;   // 4M threads, 4 elems each
  const int mat = idx >> 20;
  const size_t off = (size_t)(idx & 0xFFFFF) * 4;
  const float* W = (mat == 0) ? W0 : (mat == 1) ? W1 : (mat == 2) ? W2 : W3;
  const f32x4 v = *(const f32x4*)(W + off);
  union { u16t s[4]; uint64_t u; } o;
#pragma unroll
  for (int i = 0; i < 4; ++i) o.s[i] = f2bf(v[i]);
  *(uint64_t*)(out + (size_t)mat * (DM * DM) + off) = o.u;
}

// ---------------- RMSNorm: h = bf16( ln_w * x * rsqrt(mean(x^2)+eps) ) ----------------
__global__ __launch_bounds__(256) void rmsnorm_kernel(const float* __restrict__ x,
                                                      const float* __restrict__ w,
                                                      u16t* __restrict__ h) {
  const int row = blockIdx.x;
  const int tid = threadIdx.x;
  const float* xr = x + (size_t)row * DM + tid * 8;
  f32x4 v0 = *(const f32x4*)(xr);
  f32x4 v1 = *(const f32x4*)(xr + 4);
  float f[8];
#pragma unroll
  for (int i = 0; i < 4; ++i) { f[i] = v0[i]; f[i + 4] = v1[i]; }
  float ss = 0.f;
#pragma unroll
  for (int i = 0; i < 8; ++i) ss += f[i] * f[i];
#pragma unroll
  for (int off = 1; off < 64; off <<= 1) ss += __shfl_xor(ss, off, 64);
  __shared__ float wsum[4];
  if ((tid & 63) == 0) wsum[tid >> 6] = ss;
  __syncthreads();
  float tot = wsum[0] + wsum[1] + wsum[2] + wsum[3];
  float rs = rsqrtf(tot * (1.0f / DM) + 1e-5f);
  f32x4 w0 = *(const f32x4*)(w + tid * 8);
  f32x4 w1 = *(const f32x4*)(w + tid * 8 + 4);
  u32x4 o;
#pragma unroll
  for (int i = 0; i < 4; ++i) {
    unsigned int lo = f2bf(f[2 * i]     * ((2 * i     < 4) ? w0[2 * i]     : w1[2 * i - 4]) * rs);
    unsigned int hi = f2bf(f[2 * i + 1] * ((2 * i + 1 < 4) ? w0[2 * i + 1] : w1[2 * i - 3]) * rs);
    o[i] = lo | (hi << 16);
  }
  *(u32x4*)(h + (size_t)row * DM + tid * 8) = o;
}

// ---------------- GEMM C = A * B^T (bf16 A,B row-major, K contiguous) ----------------
// Round-3 structure: 128x128 tile, BK=32, 4 waves each 64x64 (4x4 of 16x16x32 MFMA).
// XCD-compact swizzle: consecutive blocks on one XCD share a B panel (1MB -> fits the
// per-XCD 4MB L2), attacking the 78MB-vs-32MB over-fetch seen in r3..r9 counters.
// MODE 0: QKV fused via blockIdx.z (z==2 stores transposed for Vt); bf16 C.
// MODE 1: out-proj split-K=2 via blockIdx.z: plain fp32 partial store to C0/C1.
template <int MODE>
__global__ __launch_bounds__(256) void gemm_bt(
    const u16t* __restrict__ A,
    const u16t* __restrict__ B0, const u16t* __restrict__ B1, const u16t* __restrict__ B2,
    void* __restrict__ C0, void* __restrict__ C1, void* __restrict__ C2) {
  __shared__ u16t Alds[128 * 32];
  __shared__ u16t Blds[128 * 32];
  const int tid  = threadIdx.x;
  const int wave = tid >> 6;
  const int lane = tid & 63;
  // XCD-compact bijection over the 16x16 (m,n) grid
  const int lin  = blockIdx.y * 16 + blockIdx.x;
  const int xcd  = lin & 7;
  const int sidx = lin >> 3;
  const int m0 = (sidx & 15) * 128;
  const int n0 = ((xcd << 1) | (sidx >> 4)) * 128;
  const int z  = blockIdx.z;
  const u16t* B = (MODE == 0) ? (z == 0 ? B0 : (z == 1 ? B1 : B2)) : B0;
  const int kbeg = (MODE == 1) ? z * (DM / 2) : 0;
  const int kend = (MODE == 1) ? kbeg + (DM / 2) : DM;

  const f32x4 fzero = {0.f, 0.f, 0.f, 0.f};
  f32x4 acc[4][4];
#pragma unroll
  for (int i = 0; i < 4; ++i)
#pragma unroll
    for (int j = 0; j < 4; ++j) acc[i][j] = fzero;

  const int lr = lane >> 2;   // 0..15 row within 16-row chunk
  const int lc = lane & 3;    // 0..3  8-elem column chunk
  const int mw = (wave >> 1) * 64;
  const int nw = (wave & 1) * 64;
  const int quad = lane >> 4;
  const int c16  = lane & 15;

  for (int k0 = kbeg; k0 < kend; k0 += 32) {
    __syncthreads();
#pragma unroll
    for (int c = 0; c < 2; ++c) {
      const int ch = wave * 2 + c;        // 8 chunks of 1KB each per tile
      const int r  = ch * 16 + lr;
      async_copy16(A + (size_t)(m0 + r) * DM + k0 + lc * 8, Alds + ch * 512);
      async_copy16(B + (size_t)(n0 + r) * DM + k0 + lc * 8, Blds + ch * 512);
    }
    __syncthreads();
    short8 af[4], bfr[4];
#pragma unroll
    for (int mt = 0; mt < 4; ++mt)
      af[mt] = *(const short8*)(Alds + (mw + mt * 16 + c16) * 32 + quad * 8);
#pragma unroll
    for (int nt = 0; nt < 4; ++nt)
      bfr[nt] = *(const short8*)(Blds + (nw + nt * 16 + c16) * 32 + quad * 8);
#pragma unroll
    for (int mt = 0; mt < 4; ++mt)
#pragma unroll
      for (int nt = 0; nt < 4; ++nt)
        acc[mt][nt] = __builtin_amdgcn_mfma_f32_16x16x32_bf16(af[mt], bfr[nt], acc[mt][nt], 0, 0, 0);
  }

#pragma unroll
  for (int mt = 0; mt < 4; ++mt) {
#pragma unroll
    for (int r = 0; r < 4; ++r) {
      const int row = m0 + mw + mt * 16 + quad * 4 + r;
#pragma unroll
      for (int nt = 0; nt < 4; ++nt) {
        const int col = n0 + nw + nt * 16 + c16;
        float vv = acc[mt][nt][r];
        if (MODE == 1) {
          float* C = (float*)(z == 0 ? C0 : C1);
          C[(size_t)row * DM + col] = vv;
        } else {
          u16t* C = (u16t*)(z == 0 ? C0 : (z == 1 ? C1 : C2));
          if (z == 2) C[(size_t)col * TS + row] = f2bf(vv);   // Vt[d_global][t]
          else        C[(size_t)row * DM + col] = f2bf(vv);
        }
      }
    }
  }
}

// ---------------- combine: out = x + mask_row * (P0 + P1) ----------------
__global__ __launch_bounds__(256) void combine_kernel(const float* __restrict__ P0,
                                                      const float* __restrict__ P1,
                                                      const float* __restrict__ x,
                                                      const int* __restrict__ am,
                                                      float* __restrict__ out) {
  const size_t idx = ((size_t)blockIdx.x * 256 + threadIdx.x) * 4;
  const int row = (int)(idx >> 11);           // idx / DM
  const float mk = (am[row] != 0) ? 1.f : 0.f;
  const f32x4 a = *(const f32x4*)(P0 + idx);
  const f32x4 b = *(const f32x4*)(P1 + idx);
  const f32x4 xr = *(const f32x4*)(x + idx);
  f32x4 o;
#pragma unroll
  for (int i = 0; i < 4; ++i) o[i] = xr[i] + mk * (a[i] + b[i]);
  *(f32x4*)(out + idx) = o;
}

// ---------------- RoPE in-place on Q and K (bf16), fp32 cos/sin ----------------
__global__ __launch_bounds__(256) void rope_kernel(u16t* __restrict__ Q, u16t* __restrict__ K,
                                                   const float* __restrict__ cosb,
                                                   const float* __restrict__ sinb) {
  int idx = blockIdx.x * 256 + threadIdx.x;   // 2 * 2048 * 1024 threads
  int mat = idx >> 21;
  int rem = idx & ((1 << 21) - 1);
  int t = rem >> 10;
  int p = rem & 1023;
  int head = p >> 6, d = p & 63;
  u16t* M = mat ? K : Q;
  size_t base = (size_t)t * DM + head * DH + d;
  float c = cosb[t * DH + d];
  float s = sinb[t * DH + d];
  float x1 = bf2f(M[base]);
  float x2 = bf2f(M[base + 64]);
  M[base]      = f2bf(x1 * c - x2 * s);
  M[base + 64] = f2bf(x2 * c + x1 * s);
}

// ---------------- Flash attention (causal), LDS-staged K/V, 128-key tiles ----------------
// r8 configuration (best measured): 256 threads, 64 q-rows/block, DPP softmax,
// single-buffered. 512-thread/128-q-row variant regressed (r9).
__global__ __launch_bounds__(256) void attn_kernel(const u16t* __restrict__ Q,
                                                   const u16t* __restrict__ K,
                                                   const u16t* __restrict__ Vt,
                                                   const int* __restrict__ am,
                                                   u16t* __restrict__ O) {
  __shared__ u16t Klds[128 * 128];   // [key][d], swizzled granules, 32 KB
  __shared__ u16t Vlds[128 * 128];   // [d][key], swizzled granules, 32 KB
  __shared__ u16t Plds[4][2048];     // per-wave P: 4 chunks of 16x32, 16 KB
  const int wave = threadIdx.x >> 6;
  const int lane = threadIdx.x & 63;
  const int head = blockIdx.x & (NH - 1);
  const int qt   = (TS / 64 - 1) - (blockIdx.x >> 4);   // largest q-tiles first
  const int q0   = qt * 64 + wave * 16;
  const int quad = lane >> 4;
  const int c16  = lane & 15;
  const u16t* Qh  = Q + head * DH;
  const u16t* Kh  = K + head * DH;
  const u16t* Vth = Vt + (size_t)head * DH * TS;
  u16t* Pw = Plds[wave];

  // staging lane constants: chunk = 4 rows x 16 granules (16B each)
  const int row_s = (lane >> 4);    // 0..3 row within chunk
  const int g_s   = (lane & 15);    // granule slot

  short8 qf[4];
#pragma unroll
  for (int dc = 0; dc < 4; ++dc)
    qf[dc] = *(const short8*)(Qh + (size_t)(q0 + c16) * DM + dc * 32 + quad * 8);

  const f32x4 fzero = {0.f, 0.f, 0.f, 0.f};
  float m_run[4], l_run[4];
  f32x4 o_acc[8];
#pragma unroll
  for (int r = 0; r < 4; ++r) { m_run[r] = -1e30f; l_run[r] = 0.f; }
#pragma unroll
  for (int nt = 0; nt < 8; ++nt) o_acc[nt] = fzero;

  const float scale = 0.08838834764831845f;  // 1/sqrt(128)
  const int ntiles = (qt * 64 + 191) >> 7;   // 128-wide tiles covering keys 0..q0+63

  for (int kt = 0; kt < ntiles; ++kt) {
    const int k0 = kt * 128;
    __syncthreads();   // all waves done reading previous K/V tile
    // stage K (32 chunks of 1KB) + V (32 chunks): 8+8 per wave
#pragma unroll
    for (int c = 0; c < 8; ++c) {
      const int ch = wave * 8 + c;
      const int r  = 4 * ch + row_s;           // 0..127
      const int g  = g_s ^ (r & 15);
      async_copy16(Kh + (size_t)(k0 + r) * DM + g * 8, Klds + ch * 512);
      async_copy16(Vth + (size_t)r * TS + k0 + g * 8, Vlds + ch * 512);
    }
    __syncthreads();   // drains vmcnt -> LDS tiles ready

    // S = Q K^T over 128 keys (8 groups of 16)
    f32x4 s[8];
#pragma unroll
    for (int ns = 0; ns < 8; ++ns) {
      f32x4 sa = fzero;
      const int rr = ns * 16 + c16;
#pragma unroll
      for (int dc = 0; dc < 4; ++dc) {
        short8 kf = *(const short8*)(Klds + rr * 128 + (((dc * 4 + quad) ^ c16) * 8));
        sa = __builtin_amdgcn_mfma_f32_16x16x32_bf16(qf[dc], kf, sa, 0, 0, 0);
      }
      s[ns] = sa;
    }

    // mask + scale + online softmax (DPP rotate-reduce within each 16-lane row)
    float pv[8][4], tmax[4];
#pragma unroll
    for (int r = 0; r < 4; ++r) tmax[r] = -1e30f;
#pragma unroll
    for (int ns = 0; ns < 8; ++ns) {
      const int key = k0 + ns * 16 + c16;
      const bool kok = (am[key] != 0);
#pragma unroll
      for (int r = 0; r < 4; ++r) {
        const int qrow = q0 + quad * 4 + r;
        float v = s[ns][r] * scale;
        if (key > qrow || !kok) v = -1e30f;
        pv[ns][r] = v;
        tmax[r] = fmaxf(tmax[r], v);
      }
    }
    float alpha[4], rsum[4];
#pragma unroll
    for (int r = 0; r < 4; ++r) {
      const float mn = fmaxf(m_run[r], row16_max(tmax[r]));
      alpha[r] = __expf(m_run[r] - mn);
      m_run[r] = mn;
      float rs = 0.f;
#pragma unroll
      for (int ns = 0; ns < 8; ++ns) {
        const float e = __expf(pv[ns][r] - mn);
        pv[ns][r] = e;
        rs += e;
      }
      rsum[r] = row16_sum(rs);
      l_run[r] = l_run[r] * alpha[r] + rsum[r];
    }

    // P: C-layout -> LDS (four 16x32 chunks) -> A-layout
#pragma unroll
    for (int ns = 0; ns < 8; ++ns)
#pragma unroll
      for (int r = 0; r < 4; ++r)
        Pw[(ns >> 1) * 512 + (quad * 4 + r) * 32 + (ns & 1) * 16 + c16] = f2bf(pv[ns][r]);
    asm volatile("s_waitcnt lgkmcnt(0)" ::: "memory");
    short8 pf[4];
#pragma unroll
    for (int c = 0; c < 4; ++c)
      pf[c] = *(const short8*)(Pw + c * 512 + c16 * 32 + quad * 8);

    // rescale O then accumulate P*V over 128 keys
#pragma unroll
    for (int nt = 0; nt < 8; ++nt)
#pragma unroll
      for (int r = 0; r < 4; ++r) o_acc[nt][r] *= alpha[r];
#pragma unroll
    for (int nt = 0; nt < 8; ++nt) {
      const int rr = nt * 16 + c16;
#pragma unroll
      for (int c = 0; c < 4; ++c) {
        short8 vf = *(const short8*)(Vlds + rr * 128 + (((c * 4 + quad) ^ c16) * 8));
        o_acc[nt] = __builtin_amdgcn_mfma_f32_16x16x32_bf16(pf[c], vf, o_acc[nt], 0, 0, 0);
      }
    }
  }

  // epilogue: O / l
#pragma unroll
  for (int r = 0; r < 4; ++r) {
    const float inv = 1.0f / fmaxf(l_run[r], 1e-20f);
    const int qrow = q0 + quad * 4 + r;
#pragma unroll
    for (int nt = 0; nt < 8; ++nt)
      O[(size_t)qrow * DM + head * DH + nt * 16 + c16] = f2bf(o_acc[nt][r] * inv);
  }
}

extern "C" void kernel_launch(void* const* d_in, const int* in_sizes, int n_in,
                              void* d_out, int out_size, void* d_ws, size_t ws_size,
                              hipStream_t stream) {
  const float* x    = (const float*)d_in[0];
  const float* cosb = (const float*)d_in[1];
  const float* sinb = (const float*)d_in[2];
  const int*   am   = (const int*)d_in[3];
  const float* lnw  = (const float*)d_in[4];
  const float* Wq   = (const float*)d_in[5];
  const float* Wk   = (const float*)d_in[6];
  const float* Wv   = (const float*)d_in[7];
  const float* Wo   = (const float*)d_in[8];
  float* out = (float*)d_out;

  u16t* h    = (u16t*)d_ws;                 // (T, D) bf16   [0, 8 MB)
  u16t* Q    = h + (size_t)TS * DM;         // (T, D)        [8, 16)
  u16t* K    = Q + (size_t)TS * DM;         // (T, D)        [16, 24)
  u16t* Vt   = K + (size_t)TS * DM;         // (D, T)        [24, 32)
  u16t* attn = Vt + (size_t)TS * DM;        // (T, D)        [32, 40)
  u16t* Wb   = attn + (size_t)TS * DM;      // 4 x (D, D)    [40, 72)
  u16t* Wqb = Wb;
  u16t* Wkb = Wb + (size_t)DM * DM;
  u16t* Wvb = Wb + 2 * (size_t)DM * DM;
  u16t* Wob = Wb + 3 * (size_t)DM * DM;
  // split-K partials alias h/Q (P0) and K/Vt (P1) — dead by out-proj time
  float* P0 = (float*)d_ws;                          // 16 MB fp32
  float* P1 = (float*)(((u16t*)d_ws) + 2 * (size_t)TS * DM);

  cast_weights<<<(4 * DM * DM / 4) / 256, 256, 0, stream>>>(Wq, Wk, Wv, Wo, Wb);
  rmsnorm_kernel<<<TS, 256, 0, stream>>>(x, lnw, h);
  gemm_bt<0><<<dim3(16, 16, 3), 256, 0, stream>>>(h, Wqb, Wkb, Wvb, Q, K, Vt);
  rope_kernel<<<(2 * TS * 1024) / 256, 256, 0, stream>>>(Q, K, cosb, sinb);
  attn_kernel<<<NH * (TS / 64), 256, 0, stream>>>(Q, K, Vt, am, attn);
  gemm_bt<1><<<dim3(16, 16, 2), 256, 0, stream>>>(attn, Wob, nullptr, nullptr, P0, P1, nullptr);
  combine_kernel<<<(TS * DM / 4) / 256, 256, 0, stream>>>(P0, P1, x, am, out);
}

// Round 11
// 324.708 us; speedup vs baseline: 1.0573x; 1.0205x over previous
//
#include <hip/hip_runtime.h>
#include <stdint.h>

#define TS 2048
#define DM 2048
#define NH 16
#define DH 128

typedef unsigned short u16t;
typedef __attribute__((ext_vector_type(8))) short short8;
typedef __attribute__((ext_vector_type(4))) float f32x4;
typedef __attribute__((ext_vector_type(4))) unsigned int u32x4;
typedef __attribute__((ext_vector_type(4))) unsigned short u16x4;

__device__ __forceinline__ float bf2f(u16t b) {
  return __uint_as_float(((unsigned int)b) << 16);
}
__device__ __forceinline__ u16t f2bf(float f) {
  unsigned int u = __float_as_uint(f);
  u += 0x7FFFu + ((u >> 16) & 1u);   // round-to-nearest-even
  return (u16t)(u >> 16);
}

// async global->LDS, 16B per lane. LDS dest = wave-uniform base + lane*16.
__device__ __forceinline__ void async_copy16(const u16t* g, u16t* l) {
  __builtin_amdgcn_global_load_lds((const __attribute__((address_space(1))) void*)g,
                                   (__attribute__((address_space(3))) void*)l, 16, 0, 0);
}

// DPP row_ror within 16-lane rows: pure-VALU cross-lane (vs ds_bpermute for __shfl).
#define DPP_ROR_F(x, n) __uint_as_float(__builtin_amdgcn_update_dpp( \
    0, (int)__float_as_uint(x), 0x120 | (n), 0xF, 0xF, true))

__device__ __forceinline__ float row16_max(float x) {
  x = fmaxf(x, DPP_ROR_F(x, 8));
  x = fmaxf(x, DPP_ROR_F(x, 4));
  x = fmaxf(x, DPP_ROR_F(x, 2));
  x = fmaxf(x, DPP_ROR_F(x, 1));
  return x;
}
__device__ __forceinline__ float row16_sum(float x) {
  x += DPP_ROR_F(x, 8);
  x += DPP_ROR_F(x, 4);
  x += DPP_ROR_F(x, 2);
  x += DPP_ROR_F(x, 1);
  return x;
}

// ---------------- fused: fp32->bf16 weight cast (blocks 0..16383) + RMSNorm (rest) ----
__global__ __launch_bounds__(256) void cast_rms_kernel(const float* __restrict__ W0,
                                                       const float* __restrict__ W1,
                                                       const float* __restrict__ W2,
                                                       const float* __restrict__ W3,
                                                       u16t* __restrict__ outw,
                                                       const float* __restrict__ x,
                                                       const float* __restrict__ lnw,
                                                       u16t* __restrict__ h) {
  if (blockIdx.x < 16384) {
    const int idx = blockIdx.x * 256 + threadIdx.x;   // 4M threads, 4 elems each
    const int mat = idx >> 20;
    const size_t off = (size_t)(idx & 0xFFFFF) * 4;
    const float* W = (mat == 0) ? W0 : (mat == 1) ? W1 : (mat == 2) ? W2 : W3;
    const f32x4 v = *(const f32x4*)(W + off);
    union { u16t s[4]; uint64_t u; } o;
#pragma unroll
    for (int i = 0; i < 4; ++i) o.s[i] = f2bf(v[i]);
    *(uint64_t*)(outw + (size_t)mat * (DM * DM) + off) = o.u;
    return;
  }
  const int row = blockIdx.x - 16384;
  const int tid = threadIdx.x;
  const float* xr = x + (size_t)row * DM + tid * 8;
  f32x4 v0 = *(const f32x4*)(xr);
  f32x4 v1 = *(const f32x4*)(xr + 4);
  float f[8];
#pragma unroll
  for (int i = 0; i < 4; ++i) { f[i] = v0[i]; f[i + 4] = v1[i]; }
  float ss = 0.f;
#pragma unroll
  for (int i = 0; i < 8; ++i) ss += f[i] * f[i];
#pragma unroll
  for (int off = 1; off < 64; off <<= 1) ss += __shfl_xor(ss, off, 64);
  __shared__ float wsum[4];
  if ((tid & 63) == 0) wsum[tid >> 6] = ss;
  __syncthreads();
  float tot = wsum[0] + wsum[1] + wsum[2] + wsum[3];
  float rs = rsqrtf(tot * (1.0f / DM) + 1e-5f);
  f32x4 w0 = *(const f32x4*)(lnw + tid * 8);
  f32x4 w1 = *(const f32x4*)(lnw + tid * 8 + 4);
  u32x4 o;
#pragma unroll
  for (int i = 0; i < 4; ++i) {
    unsigned int lo = f2bf(f[2 * i]     * ((2 * i     < 4) ? w0[2 * i]     : w1[2 * i - 4]) * rs);
    unsigned int hi = f2bf(f[2 * i + 1] * ((2 * i + 1 < 4) ? w0[2 * i + 1] : w1[2 * i - 3]) * rs);
    o[i] = lo | (hi << 16);
  }
  *(u32x4*)(h + (size_t)row * DM + tid * 8) = o;
}

// ---------------- GEMM C = A * B^T (bf16 A,B row-major, K contiguous) ----------------
// Round-3 structure: 128x128 tile, BK=32, 4 waves each 64x64 (4x4 of 16x16x32 MFMA).
// QKV pinned at ~104us across all inner-loop variants (r4,r6,r10) — structural plateau.
// MODE 0: QKV fused via blockIdx.z (z==2 stores transposed for Vt); bf16 C.
// MODE 1: out-proj split-K=2 via blockIdx.z: bf16 partial store to C0/C1.
template <int MODE>
__global__ __launch_bounds__(256) void gemm_bt(
    const u16t* __restrict__ A,
    const u16t* __restrict__ B0, const u16t* __restrict__ B1, const u16t* __restrict__ B2,
    void* __restrict__ C0, void* __restrict__ C1, void* __restrict__ C2) {
  __shared__ u16t Alds[128 * 32];
  __shared__ u16t Blds[128 * 32];
  const int tid  = threadIdx.x;
  const int wave = tid >> 6;
  const int lane = tid & 63;
  const int lin  = blockIdx.y * 16 + blockIdx.x;
  const int xcd  = lin & 7;
  const int sidx = lin >> 3;
  const int m0 = (sidx & 15) * 128;
  const int n0 = ((xcd << 1) | (sidx >> 4)) * 128;
  const int z  = blockIdx.z;
  const u16t* B = (MODE == 0) ? (z == 0 ? B0 : (z == 1 ? B1 : B2)) : B0;
  const int kbeg = (MODE == 1) ? z * (DM / 2) : 0;
  const int kend = (MODE == 1) ? kbeg + (DM / 2) : DM;

  const f32x4 fzero = {0.f, 0.f, 0.f, 0.f};
  f32x4 acc[4][4];
#pragma unroll
  for (int i = 0; i < 4; ++i)
#pragma unroll
    for (int j = 0; j < 4; ++j) acc[i][j] = fzero;

  const int lr = lane >> 2;   // 0..15 row within 16-row chunk
  const int lc = lane & 3;    // 0..3  8-elem column chunk
  const int mw = (wave >> 1) * 64;
  const int nw = (wave & 1) * 64;
  const int quad = lane >> 4;
  const int c16  = lane & 15;

  for (int k0 = kbeg; k0 < kend; k0 += 32) {
    __syncthreads();
#pragma unroll
    for (int c = 0; c < 2; ++c) {
      const int ch = wave * 2 + c;        // 8 chunks of 1KB each per tile
      const int r  = ch * 16 + lr;
      async_copy16(A + (size_t)(m0 + r) * DM + k0 + lc * 8, Alds + ch * 512);
      async_copy16(B + (size_t)(n0 + r) * DM + k0 + lc * 8, Blds + ch * 512);
    }
    __syncthreads();
    short8 af[4], bfr[4];
#pragma unroll
    for (int mt = 0; mt < 4; ++mt)
      af[mt] = *(const short8*)(Alds + (mw + mt * 16 + c16) * 32 + quad * 8);
#pragma unroll
    for (int nt = 0; nt < 4; ++nt)
      bfr[nt] = *(const short8*)(Blds + (nw + nt * 16 + c16) * 32 + quad * 8);
#pragma unroll
    for (int mt = 0; mt < 4; ++mt)
#pragma unroll
      for (int nt = 0; nt < 4; ++nt)
        acc[mt][nt] = __builtin_amdgcn_mfma_f32_16x16x32_bf16(af[mt], bfr[nt], acc[mt][nt], 0, 0, 0);
  }

#pragma unroll
  for (int mt = 0; mt < 4; ++mt) {
#pragma unroll
    for (int r = 0; r < 4; ++r) {
      const int row = m0 + mw + mt * 16 + quad * 4 + r;
#pragma unroll
      for (int nt = 0; nt < 4; ++nt) {
        const int col = n0 + nw + nt * 16 + c16;
        float vv = acc[mt][nt][r];
        if (MODE == 1) {
          u16t* C = (u16t*)(z == 0 ? C0 : C1);
          C[(size_t)row * DM + col] = f2bf(vv);
        } else {
          u16t* C = (u16t*)(z == 0 ? C0 : (z == 1 ? C1 : C2));
          if (z == 2) C[(size_t)col * TS + row] = f2bf(vv);   // Vt[d_global][t]
          else        C[(size_t)row * DM + col] = f2bf(vv);
        }
      }
    }
  }
}

// ---------------- combine: out = x + mask_row * (P0 + P1), bf16 partials ----------------
__global__ __launch_bounds__(256) void combine_kernel(const u16t* __restrict__ P0,
                                                      const u16t* __restrict__ P1,
                                                      const float* __restrict__ x,
                                                      const int* __restrict__ am,
                                                      float* __restrict__ out) {
  const size_t idx = ((size_t)blockIdx.x * 256 + threadIdx.x) * 4;
  const int row = (int)(idx >> 11);           // idx / DM
  const float mk = (am[row] != 0) ? 1.f : 0.f;
  const u16x4 a = *(const u16x4*)(P0 + idx);
  const u16x4 b = *(const u16x4*)(P1 + idx);
  const f32x4 xr = *(const f32x4*)(x + idx);
  f32x4 o;
#pragma unroll
  for (int i = 0; i < 4; ++i) o[i] = xr[i] + mk * (bf2f(a[i]) + bf2f(b[i]));
  *(f32x4*)(out + idx) = o;
}

// ---------------- RoPE in-place on Q and K (bf16), fp32 cos/sin ----------------
__global__ __launch_bounds__(256) void rope_kernel(u16t* __restrict__ Q, u16t* __restrict__ K,
                                                   const float* __restrict__ cosb,
                                                   const float* __restrict__ sinb) {
  int idx = blockIdx.x * 256 + threadIdx.x;   // 2 * 2048 * 1024 threads
  int mat = idx >> 21;
  int rem = idx & ((1 << 21) - 1);
  int t = rem >> 10;
  int p = rem & 1023;
  int head = p >> 6, d = p & 63;
  u16t* M = mat ? K : Q;
  size_t base = (size_t)t * DM + head * DH + d;
  float c = cosb[t * DH + d];
  float s = sinb[t * DH + d];
  float x1 = bf2f(M[base]);
  float x2 = bf2f(M[base + 64]);
  M[base]      = f2bf(x1 * c - x2 * s);
  M[base + 64] = f2bf(x2 * c + x1 * s);
}

// ---------------- Flash attention (causal), LDS-staged K/V, 128-key tiles ----------------
// r8 per-block structure (best measured). Block mapping balances per-CU load: all 512
// blocks are co-resident (80KB LDS -> exactly 2/CU); blocks x and x+256 (which share a
// CU under round-robin) get qt and 31-qt of the SAME head -> constant per-CU tile-iter
// total (was 26.5 worst / 11.5 best) + same-head K/V L2 sharing.
__global__ __launch_bounds__(256) void attn_kernel(const u16t* __restrict__ Q,
                                                   const u16t* __restrict__ K,
                                                   const u16t* __restrict__ Vt,
                                                   const int* __restrict__ am,
                                                   u16t* __restrict__ O) {
  __shared__ u16t Klds[128 * 128];   // [key][d], swizzled granules, 32 KB
  __shared__ u16t Vlds[128 * 128];   // [d][key], swizzled granules, 32 KB
  __shared__ u16t Plds[4][2048];     // per-wave P: 4 chunks of 16x32, 16 KB
  const int wave = threadIdx.x >> 6;
  const int lane = threadIdx.x & 63;
  const int x    = blockIdx.x;
  const int half = x >> 8;                  // 0: qt 31..16, 1: qt 0..15
  const int idx  = x & 255;
  const int head = idx & (NH - 1);
  const int grp  = idx >> 4;                // 0..15
  const int qt   = half ? grp : (TS / 64 - 1 - grp);
  const int q0   = qt * 64 + wave * 16;
  const int quad = lane >> 4;
  const int c16  = lane & 15;
  const u16t* Qh  = Q + head * DH;
  const u16t* Kh  = K + head * DH;
  const u16t* Vth = Vt + (size_t)head * DH * TS;
  u16t* Pw = Plds[wave];

  // staging lane constants: chunk = 4 rows x 16 granules (16B each)
  const int row_s = (lane >> 4);    // 0..3 row within chunk
  const int g_s   = (lane & 15);    // granule slot

  short8 qf[4];
#pragma unroll
  for (int dc = 0; dc < 4; ++dc)
    qf[dc] = *(const short8*)(Qh + (size_t)(q0 + c16) * DM + dc * 32 + quad * 8);

  const f32x4 fzero = {0.f, 0.f, 0.f, 0.f};
  float m_run[4], l_run[4];
  f32x4 o_acc[8];
#pragma unroll
  for (int r = 0; r < 4; ++r) { m_run[r] = -1e30f; l_run[r] = 0.f; }
#pragma unroll
  for (int nt = 0; nt < 8; ++nt) o_acc[nt] = fzero;

  const float scale = 0.08838834764831845f;  // 1/sqrt(128)
  const int ntiles = (qt * 64 + 191) >> 7;   // 128-wide tiles covering keys 0..q0+63

  for (int kt = 0; kt < ntiles; ++kt) {
    const int k0 = kt * 128;
    __syncthreads();   // all waves done reading previous K/V tile
    // stage K (32 chunks of 1KB) + V (32 chunks): 8+8 per wave
#pragma unroll
    for (int c = 0; c < 8; ++c) {
      const int ch = wave * 8 + c;
      const int r  = 4 * ch + row_s;           // 0..127
      const int g  = g_s ^ (r & 15);
      async_copy16(Kh + (size_t)(k0 + r) * DM + g * 8, Klds + ch * 512);
      async_copy16(Vth + (size_t)r * TS + k0 + g * 8, Vlds + ch * 512);
    }
    __syncthreads();   // drains vmcnt -> LDS tiles ready

    // S = Q K^T over 128 keys (8 groups of 16)
    f32x4 s[8];
#pragma unroll
    for (int ns = 0; ns < 8; ++ns) {
      f32x4 sa = fzero;
      const int rr = ns * 16 + c16;
#pragma unroll
      for (int dc = 0; dc < 4; ++dc) {
        short8 kf = *(const short8*)(Klds + rr * 128 + (((dc * 4 + quad) ^ c16) * 8));
        sa = __builtin_amdgcn_mfma_f32_16x16x32_bf16(qf[dc], kf, sa, 0, 0, 0);
      }
      s[ns] = sa;
    }

    // mask + scale + online softmax (DPP rotate-reduce within each 16-lane row)
    float pv[8][4], tmax[4];
#pragma unroll
    for (int r = 0; r < 4; ++r) tmax[r] = -1e30f;
#pragma unroll
    for (int ns = 0; ns < 8; ++ns) {
      const int key = k0 + ns * 16 + c16;
      const bool kok = (am[key] != 0);
#pragma unroll
      for (int r = 0; r < 4; ++r) {
        const int qrow = q0 + quad * 4 + r;
        float v = s[ns][r] * scale;
        if (key > qrow || !kok) v = -1e30f;
        pv[ns][r] = v;
        tmax[r] = fmaxf(tmax[r], v);
      }
    }
    float alpha[4], rsum[4];
#pragma unroll
    for (int r = 0; r < 4; ++r) {
      const float mn = fmaxf(m_run[r], row16_max(tmax[r]));
      alpha[r] = __expf(m_run[r] - mn);
      m_run[r] = mn;
      float rs = 0.f;
#pragma unroll
      for (int ns = 0; ns < 8; ++ns) {
        const float e = __expf(pv[ns][r] - mn);
        pv[ns][r] = e;
        rs += e;
      }
      rsum[r] = row16_sum(rs);
      l_run[r] = l_run[r] * alpha[r] + rsum[r];
    }

    // P: C-layout -> LDS (four 16x32 chunks) -> A-layout
#pragma unroll
    for (int ns = 0; ns < 8; ++ns)
#pragma unroll
      for (int r = 0; r < 4; ++r)
        Pw[(ns >> 1) * 512 + (quad * 4 + r) * 32 + (ns & 1) * 16 + c16] = f2bf(pv[ns][r]);
    asm volatile("s_waitcnt lgkmcnt(0)" ::: "memory");
    short8 pf[4];
#pragma unroll
    for (int c = 0; c < 4; ++c)
      pf[c] = *(const short8*)(Pw + c * 512 + c16 * 32 + quad * 8);

    // rescale O then accumulate P*V over 128 keys
#pragma unroll
    for (int nt = 0; nt < 8; ++nt)
#pragma unroll
      for (int r = 0; r < 4; ++r) o_acc[nt][r] *= alpha[r];
#pragma unroll
    for (int nt = 0; nt < 8; ++nt) {
      const int rr = nt * 16 + c16;
#pragma unroll
      for (int c = 0; c < 4; ++c) {
        short8 vf = *(const short8*)(Vlds + rr * 128 + (((c * 4 + quad) ^ c16) * 8));
        o_acc[nt] = __builtin_amdgcn_mfma_f32_16x16x32_bf16(pf[c], vf, o_acc[nt], 0, 0, 0);
      }
    }
  }

  // epilogue: O / l
#pragma unroll
  for (int r = 0; r < 4; ++r) {
    const float inv = 1.0f / fmaxf(l_run[r], 1e-20f);
    const int qrow = q0 + quad * 4 + r;
#pragma unroll
    for (int nt = 0; nt < 8; ++nt)
      O[(size_t)qrow * DM + head * DH + nt * 16 + c16] = f2bf(o_acc[nt][r] * inv);
  }
}

extern "C" void kernel_launch(void* const* d_in, const int* in_sizes, int n_in,
                              void* d_out, int out_size, void* d_ws, size_t ws_size,
                              hipStream_t stream) {
  const float* x    = (const float*)d_in[0];
  const float* cosb = (const float*)d_in[1];
  const float* sinb = (const float*)d_in[2];
  const int*   am   = (const int*)d_in[3];
  const float* lnw  = (const float*)d_in[4];
  const float* Wq   = (const float*)d_in[5];
  const float* Wk   = (const float*)d_in[6];
  const float* Wv   = (const float*)d_in[7];
  const float* Wo   = (const float*)d_in[8];
  float* out = (float*)d_out;

  u16t* h    = (u16t*)d_ws;                 // (T, D) bf16   [0, 8 MB)
  u16t* Q    = h + (size_t)TS * DM;         // (T, D)        [8, 16)
  u16t* K    = Q + (size_t)TS * DM;         // (T, D)        [16, 24)
  u16t* Vt   = K + (size_t)TS * DM;         // (D, T)        [24, 32)
  u16t* attn = Vt + (size_t)TS * DM;        // (T, D)        [32, 40)
  u16t* Wb   = attn + (size_t)TS * DM;      // 4 x (D, D)    [40, 72)
  u16t* Wqb = Wb;
  u16t* Wkb = Wb + (size_t)DM * DM;
  u16t* Wvb = Wb + 2 * (size_t)DM * DM;
  u16t* Wob = Wb + 3 * (size_t)DM * DM;
  // bf16 split-K partials alias h and Q — dead by out-proj time
  u16t* P0 = h;
  u16t* P1 = Q;

  cast_rms_kernel<<<16384 + TS, 256, 0, stream>>>(Wq, Wk, Wv, Wo, Wb, x, lnw, h);
  gemm_bt<0><<<dim3(16, 16, 3), 256, 0, stream>>>(h, Wqb, Wkb, Wvb, Q, K, Vt);
  rope_kernel<<<(2 * TS * 1024) / 256, 256, 0, stream>>>(Q, K, cosb, sinb);
  attn_kernel<<<NH * (TS / 64), 256, 0, stream>>>(Q, K, Vt, am, attn);
  gemm_bt<1><<<dim3(16, 16, 2), 256, 0, stream>>>(attn, Wob, nullptr, nullptr, P0, P1, nullptr);
  combine_kernel<<<(TS * DM / 4) / 256, 256, 0, stream>>>(P0, P1, x, am, out);
}

// Round 12
// 322.476 us; speedup vs baseline: 1.0646x; 1.0069x over previous
//
#include <hip/hip_runtime.h>
#include <stdint.h>

#define TS 2048
#define DM 2048
#define NH 16
#define DH 128

typedef unsigned short u16t;
typedef __attribute__((ext_vector_type(8))) short short8;
typedef __attribute__((ext_vector_type(4))) float f32x4;
typedef __attribute__((ext_vector_type(4))) unsigned int u32x4;
typedef __attribute__((ext_vector_type(4))) unsigned short u16x4;

__device__ __forceinline__ float bf2f(u16t b) {
  return __uint_as_float(((unsigned int)b) << 16);
}
__device__ __forceinline__ u16t f2bf(float f) {
  unsigned int u = __float_as_uint(f);
  u += 0x7FFFu + ((u >> 16) & 1u);   // round-to-nearest-even
  return (u16t)(u >> 16);
}

// async global->LDS, 16B per lane. LDS dest = wave-uniform base + lane*16.
__device__ __forceinline__ void async_copy16(const u16t* g, u16t* l) {
  __builtin_amdgcn_global_load_lds((const __attribute__((address_space(1))) void*)g,
                                   (__attribute__((address_space(3))) void*)l, 16, 0, 0);
}

// DPP row_ror within 16-lane rows: pure-VALU cross-lane (vs ds_bpermute for __shfl).
#define DPP_ROR_F(x, n) __uint_as_float(__builtin_amdgcn_update_dpp( \
    0, (int)__float_as_uint(x), 0x120 | (n), 0xF, 0xF, true))

__device__ __forceinline__ float row16_max(float x) {
  x = fmaxf(x, DPP_ROR_F(x, 8));
  x = fmaxf(x, DPP_ROR_F(x, 4));
  x = fmaxf(x, DPP_ROR_F(x, 2));
  x = fmaxf(x, DPP_ROR_F(x, 1));
  return x;
}
__device__ __forceinline__ float row16_sum(float x) {
  x += DPP_ROR_F(x, 8);
  x += DPP_ROR_F(x, 4);
  x += DPP_ROR_F(x, 2);
  x += DPP_ROR_F(x, 1);
  return x;
}

// ---------------- fused: fp32->bf16 weight cast (blocks 0..16383) + RMSNorm (rest) ----
__global__ __launch_bounds__(256) void cast_rms_kernel(const float* __restrict__ W0,
                                                       const float* __restrict__ W1,
                                                       const float* __restrict__ W2,
                                                       const float* __restrict__ W3,
                                                       u16t* __restrict__ outw,
                                                       const float* __restrict__ x,
                                                       const float* __restrict__ lnw,
                                                       u16t* __restrict__ h) {
  if (blockIdx.x < 16384) {
    const int idx = blockIdx.x * 256 + threadIdx.x;   // 4M threads, 4 elems each
    const int mat = idx >> 20;
    const size_t off = (size_t)(idx & 0xFFFFF) * 4;
    const float* W = (mat == 0) ? W0 : (mat == 1) ? W1 : (mat == 2) ? W2 : W3;
    const f32x4 v = *(const f32x4*)(W + off);
    union { u16t s[4]; uint64_t u; } o;
#pragma unroll
    for (int i = 0; i < 4; ++i) o.s[i] = f2bf(v[i]);
    *(uint64_t*)(outw + (size_t)mat * (DM * DM) + off) = o.u;
    return;
  }
  const int row = blockIdx.x - 16384;
  const int tid = threadIdx.x;
  const float* xr = x + (size_t)row * DM + tid * 8;
  f32x4 v0 = *(const f32x4*)(xr);
  f32x4 v1 = *(const f32x4*)(xr + 4);
  float f[8];
#pragma unroll
  for (int i = 0; i < 4; ++i) { f[i] = v0[i]; f[i + 4] = v1[i]; }
  float ss = 0.f;
#pragma unroll
  for (int i = 0; i < 8; ++i) ss += f[i] * f[i];
#pragma unroll
  for (int off = 1; off < 64; off <<= 1) ss += __shfl_xor(ss, off, 64);
  __shared__ float wsum[4];
  if ((tid & 63) == 0) wsum[tid >> 6] = ss;
  __syncthreads();
  float tot = wsum[0] + wsum[1] + wsum[2] + wsum[3];
  float rs = rsqrtf(tot * (1.0f / DM) + 1e-5f);
  f32x4 w0 = *(const f32x4*)(lnw + tid * 8);
  f32x4 w1 = *(const f32x4*)(lnw + tid * 8 + 4);
  u32x4 o;
#pragma unroll
  for (int i = 0; i < 4; ++i) {
    unsigned int lo = f2bf(f[2 * i]     * ((2 * i     < 4) ? w0[2 * i]     : w1[2 * i - 4]) * rs);
    unsigned int hi = f2bf(f[2 * i + 1] * ((2 * i + 1 < 4) ? w0[2 * i + 1] : w1[2 * i - 3]) * rs);
    o[i] = lo | (hi << 16);
  }
  *(u32x4*)(h + (size_t)row * DM + tid * 8) = o;
}

// ---------------- GEMM C = A * B^T (bf16 A,B row-major, K contiguous) ----------------
// 128x128 tile, BK=32, 4 waves each 64x64. QKV plateaued at 3 blocks/CU (r4..r10);
// this round: split-K=2 for QKV too -> 1536 blocks ~5-6/CU so co-resident blocks hide
// each other's barrier drains (m114). bf16 partials; combine kernel fuses RoPE.
// MODE 0: z = mat*2 + khalf; mat==2 stores transposed (Vt partials).
// MODE 1: out-proj split-K=2 via blockIdx.z: bf16 partial store to C0/C1.
template <int MODE>
__global__ __launch_bounds__(256) void gemm_bt(
    const u16t* __restrict__ A,
    const u16t* __restrict__ B0, const u16t* __restrict__ B1, const u16t* __restrict__ B2,
    u16t* __restrict__ Cq0, u16t* __restrict__ Cq1,
    u16t* __restrict__ Ck0, u16t* __restrict__ Ck1,
    u16t* __restrict__ Cv0, u16t* __restrict__ Cv1) {
  __shared__ u16t Alds[128 * 32];
  __shared__ u16t Blds[128 * 32];
  const int tid  = threadIdx.x;
  const int wave = tid >> 6;
  const int lane = tid & 63;
  const int lin  = blockIdx.y * 16 + blockIdx.x;
  const int xcd  = lin & 7;
  const int sidx = lin >> 3;
  const int m0 = (sidx & 15) * 128;
  const int n0 = ((xcd << 1) | (sidx >> 4)) * 128;
  const int z  = blockIdx.z;
  const int mat   = (MODE == 0) ? (z >> 1) : 0;
  const int khalf = (MODE == 0) ? (z & 1) : z;
  const u16t* B = (MODE == 0) ? (mat == 0 ? B0 : (mat == 1 ? B1 : B2)) : B0;
  const int kbeg = khalf * (DM / 2);
  const int kend = kbeg + (DM / 2);

  const f32x4 fzero = {0.f, 0.f, 0.f, 0.f};
  f32x4 acc[4][4];
#pragma unroll
  for (int i = 0; i < 4; ++i)
#pragma unroll
    for (int j = 0; j < 4; ++j) acc[i][j] = fzero;

  const int lr = lane >> 2;   // 0..15 row within 16-row chunk
  const int lc = lane & 3;    // 0..3  8-elem column chunk
  const int mw = (wave >> 1) * 64;
  const int nw = (wave & 1) * 64;
  const int quad = lane >> 4;
  const int c16  = lane & 15;

  for (int k0 = kbeg; k0 < kend; k0 += 32) {
    __syncthreads();
#pragma unroll
    for (int c = 0; c < 2; ++c) {
      const int ch = wave * 2 + c;        // 8 chunks of 1KB each per tile
      const int r  = ch * 16 + lr;
      async_copy16(A + (size_t)(m0 + r) * DM + k0 + lc * 8, Alds + ch * 512);
      async_copy16(B + (size_t)(n0 + r) * DM + k0 + lc * 8, Blds + ch * 512);
    }
    __syncthreads();
    short8 af[4], bfr[4];
#pragma unroll
    for (int mt = 0; mt < 4; ++mt)
      af[mt] = *(const short8*)(Alds + (mw + mt * 16 + c16) * 32 + quad * 8);
#pragma unroll
    for (int nt = 0; nt < 4; ++nt)
      bfr[nt] = *(const short8*)(Blds + (nw + nt * 16 + c16) * 32 + quad * 8);
#pragma unroll
    for (int mt = 0; mt < 4; ++mt)
#pragma unroll
      for (int nt = 0; nt < 4; ++nt)
        acc[mt][nt] = __builtin_amdgcn_mfma_f32_16x16x32_bf16(af[mt], bfr[nt], acc[mt][nt], 0, 0, 0);
  }

  u16t* C;
  if (MODE == 1) C = khalf ? Cq1 : Cq0;
  else C = (mat == 0) ? (khalf ? Cq1 : Cq0) : (mat == 1) ? (khalf ? Ck1 : Ck0) : (khalf ? Cv1 : Cv0);
  const bool transp = (MODE == 0) && (mat == 2);
#pragma unroll
  for (int mt = 0; mt < 4; ++mt) {
#pragma unroll
    for (int r = 0; r < 4; ++r) {
      const int row = m0 + mw + mt * 16 + quad * 4 + r;
#pragma unroll
      for (int nt = 0; nt < 4; ++nt) {
        const int col = n0 + nw + nt * 16 + c16;
        const u16t vv = f2bf(acc[mt][nt][r]);
        if (transp) C[(size_t)col * TS + row] = vv;
        else        C[(size_t)row * DM + col] = vv;
      }
    }
  }
}

// ---------------- qkv combine: sum split-K partials; fused RoPE for Q/K; Vt plain ----
// blocks 0..16383: Q/K pairs (in-place into *p0). blocks 16384..20479: Vt elementwise.
__global__ __launch_bounds__(256) void qkv_combine_kernel(
    u16t* __restrict__ Qp0, const u16t* __restrict__ Qp1,
    u16t* __restrict__ Kp0, const u16t* __restrict__ Kp1,
    u16t* __restrict__ Vp0, const u16t* __restrict__ Vp1,
    const float* __restrict__ cosb, const float* __restrict__ sinb) {
  if (blockIdx.x < 16384) {
    int idx = blockIdx.x * 256 + threadIdx.x;   // 2 * 2048 * 1024 threads
    int mat = idx >> 21;
    int rem = idx & ((1 << 21) - 1);
    int t = rem >> 10;
    int p = rem & 1023;
    int head = p >> 6, d = p & 63;
    u16t* M0 = mat ? Kp0 : Qp0;
    const u16t* M1 = mat ? Kp1 : Qp1;
    size_t base = (size_t)t * DM + head * DH + d;
    float c = cosb[t * DH + d];
    float s = sinb[t * DH + d];
    float x1 = bf2f(M0[base])      + bf2f(M1[base]);
    float x2 = bf2f(M0[base + 64]) + bf2f(M1[base + 64]);
    M0[base]      = f2bf(x1 * c - x2 * s);
    M0[base + 64] = f2bf(x2 * c + x1 * s);
    return;
  }
  const size_t off = ((size_t)(blockIdx.x - 16384) * 256 + threadIdx.x) * 4;
  const u16x4 a = *(const u16x4*)(Vp0 + off);
  const u16x4 b = *(const u16x4*)(Vp1 + off);
  u16x4 o;
#pragma unroll
  for (int i = 0; i < 4; ++i) o[i] = f2bf(bf2f(a[i]) + bf2f(b[i]));
  *(u16x4*)(Vp0 + off) = o;
}

// ---------------- combine: out = x + mask_row * (P0 + P1), bf16 partials ----------------
__global__ __launch_bounds__(256) void combine_kernel(const u16t* __restrict__ P0,
                                                      const u16t* __restrict__ P1,
                                                      const float* __restrict__ x,
                                                      const int* __restrict__ am,
                                                      float* __restrict__ out) {
  const size_t idx = ((size_t)blockIdx.x * 256 + threadIdx.x) * 4;
  const int row = (int)(idx >> 11);           // idx / DM
  const float mk = (am[row] != 0) ? 1.f : 0.f;
  const u16x4 a = *(const u16x4*)(P0 + idx);
  const u16x4 b = *(const u16x4*)(P1 + idx);
  const f32x4 xr = *(const f32x4*)(x + idx);
  f32x4 o;
#pragma unroll
  for (int i = 0; i < 4; ++i) o[i] = xr[i] + mk * (bf2f(a[i]) + bf2f(b[i]));
  *(f32x4*)(out + idx) = o;
}

// ---------------- Flash attention (causal), LDS-staged K/V, 128-key tiles ----------------
// r8 per-block structure + r11 balanced mapping (kept; harmless).
__global__ __launch_bounds__(256) void attn_kernel(const u16t* __restrict__ Q,
                                                   const u16t* __restrict__ K,
                                                   const u16t* __restrict__ Vt,
                                                   const int* __restrict__ am,
                                                   u16t* __restrict__ O) {
  __shared__ u16t Klds[128 * 128];   // [key][d], swizzled granules, 32 KB
  __shared__ u16t Vlds[128 * 128];   // [d][key], swizzled granules, 32 KB
  __shared__ u16t Plds[4][2048];     // per-wave P: 4 chunks of 16x32, 16 KB
  const int wave = threadIdx.x >> 6;
  const int lane = threadIdx.x & 63;
  const int x    = blockIdx.x;
  const int half = x >> 8;                  // 0: qt 31..16, 1: qt 0..15
  const int idx  = x & 255;
  const int head = idx & (NH - 1);
  const int grp  = idx >> 4;                // 0..15
  const int qt   = half ? grp : (TS / 64 - 1 - grp);
  const int q0   = qt * 64 + wave * 16;
  const int quad = lane >> 4;
  const int c16  = lane & 15;
  const u16t* Qh  = Q + head * DH;
  const u16t* Kh  = K + head * DH;
  const u16t* Vth = Vt + (size_t)head * DH * TS;
  u16t* Pw = Plds[wave];

  const int row_s = (lane >> 4);    // 0..3 row within chunk
  const int g_s   = (lane & 15);    // granule slot

  short8 qf[4];
#pragma unroll
  for (int dc = 0; dc < 4; ++dc)
    qf[dc] = *(const short8*)(Qh + (size_t)(q0 + c16) * DM + dc * 32 + quad * 8);

  const f32x4 fzero = {0.f, 0.f, 0.f, 0.f};
  float m_run[4], l_run[4];
  f32x4 o_acc[8];
#pragma unroll
  for (int r = 0; r < 4; ++r) { m_run[r] = -1e30f; l_run[r] = 0.f; }
#pragma unroll
  for (int nt = 0; nt < 8; ++nt) o_acc[nt] = fzero;

  const float scale = 0.08838834764831845f;  // 1/sqrt(128)
  const int ntiles = (qt * 64 + 191) >> 7;   // 128-wide tiles covering keys 0..q0+63

  for (int kt = 0; kt < ntiles; ++kt) {
    const int k0 = kt * 128;
    __syncthreads();
#pragma unroll
    for (int c = 0; c < 8; ++c) {
      const int ch = wave * 8 + c;
      const int r  = 4 * ch + row_s;           // 0..127
      const int g  = g_s ^ (r & 15);
      async_copy16(Kh + (size_t)(k0 + r) * DM + g * 8, Klds + ch * 512);
      async_copy16(Vth + (size_t)r * TS + k0 + g * 8, Vlds + ch * 512);
    }
    __syncthreads();

    f32x4 s[8];
#pragma unroll
    for (int ns = 0; ns < 8; ++ns) {
      f32x4 sa = fzero;
      const int rr = ns * 16 + c16;
#pragma unroll
      for (int dc = 0; dc < 4; ++dc) {
        short8 kf = *(const short8*)(Klds + rr * 128 + (((dc * 4 + quad) ^ c16) * 8));
        sa = __builtin_amdgcn_mfma_f32_16x16x32_bf16(qf[dc], kf, sa, 0, 0, 0);
      }
      s[ns] = sa;
    }

    float pv[8][4], tmax[4];
#pragma unroll
    for (int r = 0; r < 4; ++r) tmax[r] = -1e30f;
#pragma unroll
    for (int ns = 0; ns < 8; ++ns) {
      const int key = k0 + ns * 16 + c16;
      const bool kok = (am[key] != 0);
#pragma unroll
      for (int r = 0; r < 4; ++r) {
        const int qrow = q0 + quad * 4 + r;
        float v = s[ns][r] * scale;
        if (key > qrow || !kok) v = -1e30f;
        pv[ns][r] = v;
        tmax[r] = fmaxf(tmax[r], v);
      }
    }
    float alpha[4], rsum[4];
#pragma unroll
    for (int r = 0; r < 4; ++r) {
      const float mn = fmaxf(m_run[r], row16_max(tmax[r]));
      alpha[r] = __expf(m_run[r] - mn);
      m_run[r] = mn;
      float rs = 0.f;
#pragma unroll
      for (int ns = 0; ns < 8; ++ns) {
        const float e = __expf(pv[ns][r] - mn);
        pv[ns][r] = e;
        rs += e;
      }
      rsum[r] = row16_sum(rs);
      l_run[r] = l_run[r] * alpha[r] + rsum[r];
    }

#pragma unroll
    for (int ns = 0; ns < 8; ++ns)
#pragma unroll
      for (int r = 0; r < 4; ++r)
        Pw[(ns >> 1) * 512 + (quad * 4 + r) * 32 + (ns & 1) * 16 + c16] = f2bf(pv[ns][r]);
    asm volatile("s_waitcnt lgkmcnt(0)" ::: "memory");
    short8 pf[4];
#pragma unroll
    for (int c = 0; c < 4; ++c)
      pf[c] = *(const short8*)(Pw + c * 512 + c16 * 32 + quad * 8);

#pragma unroll
    for (int nt = 0; nt < 8; ++nt)
#pragma unroll
      for (int r = 0; r < 4; ++r) o_acc[nt][r] *= alpha[r];
#pragma unroll
    for (int nt = 0; nt < 8; ++nt) {
      const int rr = nt * 16 + c16;
#pragma unroll
      for (int c = 0; c < 4; ++c) {
        short8 vf = *(const short8*)(Vlds + rr * 128 + (((c * 4 + quad) ^ c16) * 8));
        o_acc[nt] = __builtin_amdgcn_mfma_f32_16x16x32_bf16(pf[c], vf, o_acc[nt], 0, 0, 0);
      }
    }
  }

#pragma unroll
  for (int r = 0; r < 4; ++r) {
    const float inv = 1.0f / fmaxf(l_run[r], 1e-20f);
    const int qrow = q0 + quad * 4 + r;
#pragma unroll
    for (int nt = 0; nt < 8; ++nt)
      O[(size_t)qrow * DM + head * DH + nt * 16 + c16] = f2bf(o_acc[nt][r] * inv);
  }
}

extern "C" void kernel_launch(void* const* d_in, const int* in_sizes, int n_in,
                              void* d_out, int out_size, void* d_ws, size_t ws_size,
                              hipStream_t stream) {
  const float* x    = (const float*)d_in[0];
  const float* cosb = (const float*)d_in[1];
  const float* sinb = (const float*)d_in[2];
  const int*   am   = (const int*)d_in[3];
  const float* lnw  = (const float*)d_in[4];
  const float* Wq   = (const float*)d_in[5];
  const float* Wk   = (const float*)d_in[6];
  const float* Wv   = (const float*)d_in[7];
  const float* Wo   = (const float*)d_in[8];
  float* out = (float*)d_out;

  u16t* h    = (u16t*)d_ws;                 // (T, D) bf16   [0, 8 MB)   ; out-proj P0
  u16t* Q    = h + (size_t)TS * DM;         // Qp0 -> Q      [8, 16)     ; out-proj P1
  u16t* K    = Q + (size_t)TS * DM;         // Kp0 -> K      [16, 24)
  u16t* Vt   = K + (size_t)TS * DM;         // Vp0 -> Vt     [24, 32)
  u16t* attn = Vt + (size_t)TS * DM;        // Qp1 ; attn out [32, 40)
  u16t* Wb   = attn + (size_t)TS * DM;      // 4 x (D, D)    [40, 72)
  u16t* Wqb = Wb;
  u16t* Wkb = Wb + (size_t)DM * DM;
  u16t* Wvb = Wb + 2 * (size_t)DM * DM;
  u16t* Wob = Wb + 3 * (size_t)DM * DM;
  // z=1 QKV partials use d_out (16 MB fp32) as scratch — dead before final combine
  u16t* Qp1 = attn;
  u16t* Kp1 = (u16t*)d_out;
  u16t* Vp1 = (u16t*)d_out + (size_t)TS * DM;

  cast_rms_kernel<<<16384 + TS, 256, 0, stream>>>(Wq, Wk, Wv, Wo, Wb, x, lnw, h);
  // QKV split-K=2: 1536 blocks (~5-6/CU) so co-resident blocks hide barrier drains
  gemm_bt<0><<<dim3(16, 16, 6), 256, 0, stream>>>(h, Wqb, Wkb, Wvb,
                                                  Q, Qp1, K, Kp1, Vt, Vp1);
  qkv_combine_kernel<<<16384 + 4096, 256, 0, stream>>>(Q, Qp1, K, Kp1, Vt, Vp1, cosb, sinb);
  attn_kernel<<<NH * (TS / 64), 256, 0, stream>>>(Q, K, Vt, am, attn);
  gemm_bt<1><<<dim3(16, 16, 2), 256, 0, stream>>>(attn, Wob, nullptr, nullptr,
                                                  h, Q, nullptr, nullptr, nullptr, nullptr);
  combine_kernel<<<(TS * DM / 4) / 256, 256, 0, stream>>>(h, Q, x, am, out);
}